// Round 11
// baseline (128.756 us; speedup 1.0000x reference)
//
#include <hip/hip_runtime.h>
#include <hip/hip_fp16.h>

#define NS 256
#define N2 (NS * NS)          // 65536
#define HID 32
#define T_STEPS 64

typedef _Float16 h2     __attribute__((ext_vector_type(2)));
typedef _Float16 half8  __attribute__((ext_vector_type(8)));
typedef float    float4v __attribute__((ext_vector_type(4)));

union H8 { half8 v8; h2 v2[4]; };

// cvt_pkrtz returns __fp16x2; bit-identical to our h2 (_Float16x2)
__device__ __forceinline__ h2 pk(float a, float b) {
    return __builtin_bit_cast(h2, __builtin_amdgcn_cvt_pkrtz(a, b));
}

// packed-f16 ELU: max(z, exp2(min(z,0)*log2e) - 1)
__device__ __forceinline__ h2 elu2(h2 z) {
    h2 zero; zero[0] = (_Float16)0.f; zero[1] = (_Float16)0.f;
    h2 zm  = __builtin_elementwise_min(z, zero);
    h2 e   = __builtin_elementwise_exp2(zm * (_Float16)1.442695041f);
    h2 em1 = e + (_Float16)(-1.0f);
    return __builtin_elementwise_max(z, em1);
}

__global__ __launch_bounds__(256, 4) void mlpconv_pipe4_kernel(
    const float* __restrict__ x,
    const float* __restrict__ W0, const float* __restrict__ b0,
    const float* __restrict__ W1, const float* __restrict__ b1,
    const float* __restrict__ W2, const float* __restrict__ b2,
    float* __restrict__ out)
{
    const int lane = threadIdx.x & 63;
    const int m    = lane & 15;   // point col (B col / C-D col / A row)
    const int kg   = lane >> 4;   // k-group: this lane's A/B k-slots are 8kg..8kg+7

    // Channel permutation so each MFMA's D lands directly in the next MFMA's
    // B-frag layout (validated round 7).
    const int c0 = 8 * (m >> 2) + (m & 3);
    const int c1 = c0 + 4;

    // ---- persistent MFMA fragments ----
    H8 a00, a01;          // layer-0 A = W0^T permuted, k>=5 rows zero
    #pragma unroll
    for (int i = 0; i < 8; ++i) {
        const int k = 8 * kg + i;
        a00.v8[i] = (k < 5) ? (_Float16)W0[k * HID + c0] : (_Float16)0.f;
        a01.v8[i] = (k < 5) ? (_Float16)W0[k * HID + c1] : (_Float16)0.f;
    }
    H8 a10, a11;          // layer-1 A = W1^T permuted
    #pragma unroll
    for (int i = 0; i < 8; ++i) {
        a10.v8[i] = (_Float16)W1[(8 * kg + i) * HID + c0];
        a11.v8[i] = (_Float16)W1[(8 * kg + i) * HID + c1];
    }
    H8 a2;                // layer-2 A: row 0 = W2, other rows zero
    #pragma unroll
    for (int i = 0; i < 8; ++i)
        a2.v8[i] = (m == 0) ? (_Float16)W2[8 * kg + i] : (_Float16)0.f;

    float4v cl0a, cl0b, cl1a, cl1b;   // biases pre-placed in C/D layout
    #pragma unroll
    for (int r = 0; r < 4; ++r) {
        cl0a[r] = b0[8 * kg + r];
        cl0b[r] = b0[8 * kg + 4 + r];
        cl1a[r] = b1[8 * kg + r];
        cl1b[r] = b1[8 * kg + 4 + r];
    }
    float4v c2;
    c2[0] = (kg == 0) ? b2[0] : 0.0f;
    c2[1] = 0.0f; c2[2] = 0.0f; c2[3] = 0.0f;

    asm volatile("" : "+v"(a00.v8), "+v"(a01.v8), "+v"(a10.v8), "+v"(a11.v8),
                      "+v"(a2.v8), "+v"(cl0a), "+v"(cl0b), "+v"(cl1a), "+v"(cl1b));

    // ---- wave -> one grid row ----
    const int wid   = __builtin_amdgcn_readfirstlane(threadIdx.x >> 6);
    const int t     = blockIdx.y;
    const int i0    = blockIdx.x * 4 + wid;      // grid row (SGPR)
    const int sbase = i0 << 8;

    const float* __restrict__ xt  = x + ((size_t)t << 16);
    const float* __restrict__ xtu = xt + ((i0 == 0)      ? (N2 - NS) : -NS);
    const float* __restrict__ xtd = xt + ((i0 == NS - 1) ? -(N2 - NS) : NS);
    float* __restrict__       ob  = out + ((size_t)t << 16);

    const unsigned vc0 = (unsigned)(sbase + m);
    const unsigned vl0 = (unsigned)(sbase + m - 1);          // valid except s==0
    const unsigned vlA = (sbase + m == 0) ? (unsigned)(N2 - 1) : vl0;  // iter-0 fix
    const unsigned vr0 = (unsigned)(sbase + m + 1);
    const unsigned vrF = (m == 15) ? (unsigned)sbase : (vr0 + 240u);   // iter-15 fix

    // channel order [l, l2, c, r, r2] == W0 rows 0..4 (validated r1-r7)
    #define LOADS(l, dst)                                                \
    {                                                                    \
        const unsigned o = 16u * (unsigned)(l);                          \
        dst[0] = xt [((l) == 0)  ? vlA : (vl0 + o)];                     \
        dst[1] = xtu[vc0 + o];                                           \
        dst[2] = xt [vc0 + o];                                           \
        dst[3] = xt [((l) == 15) ? vrF : (vr0 + o)];                     \
        dst[4] = xtd[vc0 + o];                                           \
    }

    // 4-slot rotating buffer, 3-deep lookahead: prefetch slot (l+3)%4 is
    // NEVER the live slot l%4 (the round-9 bug was in[3] with %3 collision).
    float in[4][5];
    float res[16];

    LOADS(0, in[0])
    LOADS(1, in[1])
    LOADS(2, in[2])

    #pragma unroll
    for (int l = 0; l < 16; ++l) {
        if (l + 3 < 16) LOADS(l + 3, in[(l + 3) % 4])

        const float* s = in[l % 4];

        // B-frag for layer 0: k-slots 0..4 = inputs; rest finite filler.
        H8 bf;
        bf.v2[0] = pk(s[0], s[1]);
        bf.v2[1] = pk(s[2], s[3]);
        bf.v2[2] = pk(s[4], s[4]);
        bf.v2[3] = bf.v2[2];

        // layer 0
        float4v d0 = __builtin_amdgcn_mfma_f32_16x16x32_f16(a00.v8, bf.v8, cl0a, 0, 0, 0);
        float4v d1 = __builtin_amdgcn_mfma_f32_16x16x32_f16(a01.v8, bf.v8, cl0b, 0, 0, 0);

        H8 hf;
        hf.v2[0] = elu2(pk(d0[0], d0[1]));
        hf.v2[1] = elu2(pk(d0[2], d0[3]));
        hf.v2[2] = elu2(pk(d1[0], d1[1]));
        hf.v2[3] = elu2(pk(d1[2], d1[3]));

        // layer 1
        float4v e0 = __builtin_amdgcn_mfma_f32_16x16x32_f16(a10.v8, hf.v8, cl1a, 0, 0, 0);
        float4v e1 = __builtin_amdgcn_mfma_f32_16x16x32_f16(a11.v8, hf.v8, cl1b, 0, 0, 0);

        H8 gf;
        gf.v2[0] = elu2(pk(e0[0], e0[1]));
        gf.v2[1] = elu2(pk(e0[2], e0[3]));
        gf.v2[2] = elu2(pk(e1[0], e1[1]));
        gf.v2[3] = elu2(pk(e1[2], e1[3]));

        // layer 2: D row 0 (kg==0, r==0) = b2 + sum_k W2[k]*gf[k]
        float4v dz = __builtin_amdgcn_mfma_f32_16x16x32_f16(a2.v8, gf.v8, c2, 0, 0, 0);

        res[l] = dz[0];
    }
    #undef LOADS

    // One divergent region instead of 16: kg==0 lanes hold all results.
    if (kg == 0) {
        #pragma unroll
        for (int l = 0; l < 16; ++l)
            ob[vc0 + 16u * (unsigned)l] = res[l];
    }
}

extern "C" void kernel_launch(void* const* d_in, const int* in_sizes, int n_in,
                              void* d_out, int out_size, void* d_ws, size_t ws_size,
                              hipStream_t stream) {
    const float* x  = (const float*)d_in[0];
    const float* W0 = (const float*)d_in[1];
    const float* b0 = (const float*)d_in[2];
    const float* W1 = (const float*)d_in[3];
    const float* b1 = (const float*)d_in[4];
    const float* W2 = (const float*)d_in[5];
    const float* b2 = (const float*)d_in[6];
    float* out = (float*)d_out;

    dim3 grid(NS / 4, T_STEPS);   // 64 x 64 blocks; block = 4 waves = 4 rows
    mlpconv_pipe4_kernel<<<grid, dim3(256), 0, stream>>>(
        x, W0, b0, W1, b1, W2, b2, out);
}

// Round 12
// 124.444 us; speedup vs baseline: 1.0347x; 1.0347x over previous
//
#include <hip/hip_runtime.h>
#include <hip/hip_fp16.h>

#define NS 256
#define N2 (NS * NS)          // 65536
#define HID 32
#define T_STEPS 64

typedef _Float16 h2      __attribute__((ext_vector_type(2)));
typedef _Float16 half8   __attribute__((ext_vector_type(8)));
typedef float    float16v __attribute__((ext_vector_type(16)));

union H8 { half8 v8; h2 v2[4]; };

// cvt_pkrtz returns __fp16x2; bit-identical to our h2 (_Float16x2)
__device__ __forceinline__ h2 pk(float a, float b) {
    return __builtin_bit_cast(h2, __builtin_amdgcn_cvt_pkrtz(a, b));
}

// packed-f16 ELU: max(z, exp2(min(z,0)*log2e) - 1)
__device__ __forceinline__ h2 elu2(h2 z) {
    h2 zero; zero[0] = (_Float16)0.f; zero[1] = (_Float16)0.f;
    h2 zm  = __builtin_elementwise_min(z, zero);
    h2 e   = __builtin_elementwise_exp2(zm * (_Float16)1.442695041f);
    h2 em1 = e + (_Float16)(-1.0f);
    return __builtin_elementwise_max(z, em1);
}

__global__ __launch_bounds__(256, 2) void mlpconv_3232_kernel(
    const float* __restrict__ x,
    const float* __restrict__ W0, const float* __restrict__ b0,
    const float* __restrict__ W1, const float* __restrict__ b1,
    const float* __restrict__ W2, const float* __restrict__ b2,
    float* __restrict__ out)
{
    const int lane = threadIdx.x & 63;
    const int c    = lane & 31;   // point col (B/C/D col) & A natural row
    const int h    = lane >> 5;   // k-half: this lane's A/B k-slots are 8h..8h+7
    const int kb   = 8 * h;

    // A-row permutation P so that D(reg,h) = channel needed by the NEXT MFMA's
    // B-slot: B#0 k-slot (8h+i) <- D reg i ; B#1 k-slot (8h+i) <- D reg 8+i.
    // D natural row r = (reg&3) + 8*(reg>>2) + 4h ; desired channel
    // c(reg,h) = reg<8 ? 8h+reg : 16+8h+(reg-8).  With r = b + 4hh + 8q:
    // P(r) = 16*(q>>1) + 8*hh + 4*(q&1) + b  satisfies channel(reg,h)=c(reg,h).
    const int rr = c;
    const int Pb = rr & 3, Ph = (rr >> 2) & 1, Pq = rr >> 3;
    const int P  = 16 * (Pq >> 1) + 8 * Ph + 4 * (Pq & 1) + Pb;

    // ---- persistent MFMA fragments ----
    H8 a0, a1a, a1b, a2a, a2b;
    #pragma unroll
    for (int i = 0; i < 8; ++i) {
        const int k = kb + i;
        a0.v8[i]  = (k < 5) ? (_Float16)W0[k * HID + P] : (_Float16)0.f;  // L0: K=5<=16
        a1a.v8[i] = (_Float16)W1[k * HID + P];          // L1 k-split 0..15
        a1b.v8[i] = (_Float16)W1[(16 + k) * HID + P];   // L1 k-split 16..31
        a2a.v8[i] = (rr == 0) ? (_Float16)W2[k]      : (_Float16)0.f;  // L2 row 0 only
        a2b.v8[i] = (rr == 0) ? (_Float16)W2[16 + k] : (_Float16)0.f;
    }

    // C-inits: biases pre-placed at the permuted channel of each (reg,h) slot.
    float16v c0i, c1i, c2i;
    #pragma unroll
    for (int reg = 0; reg < 16; ++reg) {
        const int ch = (reg < 8) ? (8 * h + reg) : (16 + 8 * h + (reg - 8));
        c0i[reg] = b0[ch];
        c1i[reg] = b1[ch];
        c2i[reg] = 0.0f;
    }
    if (h == 0) c2i[0] = b2[0];   // D row 0 = (reg0, h0)

    asm volatile("" : "+v"(a0.v8), "+v"(a1a.v8), "+v"(a1b.v8),
                      "+v"(a2a.v8), "+v"(a2b.v8),
                      "+v"(c0i), "+v"(c1i), "+v"(c2i));

    // ---- wave -> one grid row (8 tiles of 32 points) ----
    const int wid   = __builtin_amdgcn_readfirstlane(threadIdx.x >> 6);
    const int t     = blockIdx.y;
    const int i0    = blockIdx.x * 4 + wid;      // grid row (SGPR)
    const int sbase = i0 << 8;

    const float* __restrict__ xt  = x + ((size_t)t << 16);
    const float* __restrict__ xtu = xt + ((i0 == 0)      ? (N2 - NS) : -NS);
    const float* __restrict__ xtd = xt + ((i0 == NS - 1) ? -(N2 - NS) : NS);
    float* __restrict__       ob  = out + ((size_t)t << 16);

    const unsigned vc0 = (unsigned)(sbase + c);
    const unsigned vl0 = (unsigned)(sbase + c - 1);
    const unsigned vlA = (sbase + c == 0) ? (unsigned)(N2 - 1) : vl0;   // tile-0 fix
    const unsigned vr0 = (unsigned)(sbase + c + 1);
    const unsigned vrF = (c == 31) ? (unsigned)sbase : (vr0 + 224u);    // tile-7 fix

    // All 40 loads upfront: independent, deep vmcnt queue, max overlap.
    // channel order [l, l2, c, r, r2] == W0 rows 0..4 (validated r1-r11)
    float in_[8][5];
    #pragma unroll
    for (int tl = 0; tl < 8; ++tl) {
        const unsigned o = 32u * (unsigned)tl;
        in_[tl][0] = xt [(tl == 0) ? vlA : (vl0 + o)];
        in_[tl][1] = xtu[vc0 + o];
        in_[tl][2] = xt [vc0 + o];
        in_[tl][3] = xt [(tl == 7) ? vrF : (vr0 + o)];
        in_[tl][4] = xtd[vc0 + o];
    }

    float res[8];

    #pragma unroll
    for (int tl = 0; tl < 8; ++tl) {
        const float* s = in_[tl];

        // L0 B-frag: k-slots 0..4 = inputs (h=0 lanes); h=1 lanes & slots >=5
        // multiply A's zero rows -> finite don't-care.
        H8 bf;
        bf.v2[0] = pk(s[0], s[1]);
        bf.v2[1] = pk(s[2], s[3]);
        bf.v2[2] = pk(s[4], s[4]);
        bf.v2[3] = bf.v2[2];

        // layer 0: one MFMA (K=5 <= 16); D reg i = channel 8h+i / 16+8h+(i-8)
        float16v d0 = __builtin_amdgcn_mfma_f32_32x32x16_f16(a0.v8, bf.v8, c0i, 0, 0, 0);

        // ELU + pack straight into the two L1 B-frags (k-split halves)
        H8 hf1, hf2;
        #pragma unroll
        for (int j = 0; j < 4; ++j) {
            hf1.v2[j] = elu2(pk(d0[2 * j],     d0[2 * j + 1]));
            hf2.v2[j] = elu2(pk(d0[8 + 2 * j], d0[8 + 2 * j + 1]));
        }

        // layer 1: K=32 via two chained MFMAs
        float16v e = __builtin_amdgcn_mfma_f32_32x32x16_f16(a1a.v8, hf1.v8, c1i, 0, 0, 0);
        e = __builtin_amdgcn_mfma_f32_32x32x16_f16(a1b.v8, hf2.v8, e, 0, 0, 0);

        H8 gf1, gf2;
        #pragma unroll
        for (int j = 0; j < 4; ++j) {
            gf1.v2[j] = elu2(pk(e[2 * j],     e[2 * j + 1]));
            gf2.v2[j] = elu2(pk(e[8 + 2 * j], e[8 + 2 * j + 1]));
        }

        // layer 2: K=32 via two chained MFMAs; D row 0 = b2 + sum W2[k]*gf[k]
        float16v dz = __builtin_amdgcn_mfma_f32_32x32x16_f16(a2a.v8, gf1.v8, c2i, 0, 0, 0);
        dz = __builtin_amdgcn_mfma_f32_32x32x16_f16(a2b.v8, gf2.v8, dz, 0, 0, 0);

        res[tl] = dz[0];
    }

    // Single divergent region: h==0 lanes hold row 0 (= the output) per col.
    if (h == 0) {
        #pragma unroll
        for (int tl = 0; tl < 8; ++tl)
            ob[vc0 + 32u * (unsigned)tl] = res[tl];
    }
}

extern "C" void kernel_launch(void* const* d_in, const int* in_sizes, int n_in,
                              void* d_out, int out_size, void* d_ws, size_t ws_size,
                              hipStream_t stream) {
    const float* x  = (const float*)d_in[0];
    const float* W0 = (const float*)d_in[1];
    const float* b0 = (const float*)d_in[2];
    const float* W1 = (const float*)d_in[3];
    const float* b1 = (const float*)d_in[4];
    const float* W2 = (const float*)d_in[5];
    const float* b2 = (const float*)d_in[6];
    float* out = (float*)d_out;

    dim3 grid(NS / 4, T_STEPS);   // 64 x 64 blocks; block = 4 waves = 4 rows
    mlpconv_3232_kernel<<<grid, dim3(256), 0, stream>>>(
        x, W0, b0, W1, b1, W2, b2, out);
}